// Round 8
// baseline (454.864 us; speedup 1.0000x reference)
//
#include <hip/hip_runtime.h>
#include <hip/hip_bf16.h>
#include <math.h>

#define C 128
#define LMAX 64
#define EPS 1e-5f
#define ISQ 0.17677669529663687f   // 1/sqrt(32)
#define WF_LO 327680               // short offset of lo-fragment table

using short8  = __attribute__((ext_vector_type(8))) short;
using f32x4   = __attribute__((ext_vector_type(4))) float;

#define WSYNC() do { asm volatile("s_waitcnt lgkmcnt(0)" ::: "memory"); __builtin_amdgcn_sched_barrier(0); } while(0)

__device__ __forceinline__ float wsum(float v){
  #pragma unroll
  for (int o = 32; o > 0; o >>= 1) v += __shfl_xor(v, o, 64);
  return v;
}
__device__ __forceinline__ float wmax(float v){
  #pragma unroll
  for (int o = 32; o > 0; o >>= 1) v = fmaxf(v, __shfl_xor(v, o, 64));
  return v;
}
__device__ __forceinline__ short f2bs(float f){
  __hip_bfloat16 b = __float2bfloat16(f);   // RNE
  union { __hip_bfloat16 b; short u; } cv; cv.b = b; return cv.u;
}
__device__ __forceinline__ float b2f(short u){
  return __uint_as_float(((unsigned)(unsigned short)u) << 16);
}
__device__ __forceinline__ unsigned pack2(float a, float b){
  return (unsigned)(unsigned short)f2bs(a) | ((unsigned)(unsigned short)f2bs(b) << 16);
}

// ---- weight fragments (hi+lo split): B-operand layout for mfma_f32_16x16x32_bf16 ----
// lane l, j -> W[kt*32 + (l>>4)*8 + j][nt*16 + (l&15)]
__global__ void prep_wfrag(const float* __restrict__ Wq, const float* __restrict__ Wk,
                           const float* __restrict__ Wv, const float* __restrict__ Wo,
                           const float* __restrict__ Wlin, short* __restrict__ wf){
  int bid = blockIdx.x, l = threadIdx.x;
  int tile = bid & 31, mb = bid >> 5;       // mb = mat*4+blk, 0..19
  int mat = mb >> 2, blk = mb & 3;
  const float* W = (mat==0?Wq : mat==1?Wk : mat==2?Wv : mat==3?Wo : Wlin) + blk*C*C;
  int nt = tile >> 2, kt = tile & 3;
  int col = nt*16 + (l & 15);
  int k0  = kt*32 + ((l >> 4) << 3);
  short8 vhi, vlo;
  #pragma unroll
  for (int j = 0; j < 8; j++){
    float wv = W[(k0 + j)*C + col];
    short h = f2bs(wv);
    vhi[j] = h;
    vlo[j] = f2bs(wv - b2f(h));
  }
  size_t off = ((size_t)mb*32 + tile)*512 + (size_t)l*8;
  *(short8*)(wf + off) = vhi;
  *(short8*)(wf + WF_LO + off) = vlo;
}

__global__ void prep_qrow(const float* __restrict__ seed, const float* __restrict__ Wq,
                          const float* __restrict__ bq, float* __restrict__ qrow){
  int t = threadIdx.x;
  const float* wq2 = Wq + 2*C*C;
  float acc = bq[2*C + t];
  #pragma unroll 4
  for (int k = 0; k < C; k++) acc = fmaf(seed[k], wq2[k*C + t], acc);
  qrow[t] = acc;
}

// ---- segment bounds + class ranks ----
__global__ void seg_kernel(const int* __restrict__ gidx, int E, int G,
                           int* __restrict__ starts, int* __restrict__ counts,
                           int* __restrict__ cnt, int* __restrict__ gcr){
  int g = blockIdx.x * blockDim.x + threadIdx.x;
  if (g >= G) return;
  int lo = 0, hi = E;
  while (lo < hi){ int m = (lo + hi) >> 1; if (gidx[m] < g) lo = m + 1; else hi = m; }
  int s = lo; hi = E;
  while (lo < hi){ int m = (lo + hi) >> 1; if (gidx[m] < g + 1) lo = m + 1; else hi = m; }
  starts[g] = s;
  int c_ = lo - s; counts[g] = c_;
  int L = c_ > LMAX ? LMAX : c_; if (L < 1) L = 1;
  int cl = (L - 1) >> 4;
  int r = atomicAdd(&cnt[cl], 1);
  gcr[g] = (cl << 28) | r;
}

__global__ void fill_kernel(int G, const int* __restrict__ cnt, const int* __restrict__ gcr,
                            int* __restrict__ binfo, int* __restrict__ nbins){
  int g = blockIdx.x * blockDim.x + threadIdx.x;
  if (g >= G) return;
  int nb1 = (cnt[0] + 3) >> 2, nb2 = (cnt[1] + 1) >> 1, nb3 = cnt[2];
  if (g == 0) *nbins = nb1 + nb2 + nb3 + cnt[3];
  int v = gcr[g]; int cl = v >> 28; int r = v & 0x0FFFFFFF;
  int bin, slot;
  if      (cl == 0){ bin = r >> 2;             slot = r & 3; }
  else if (cl == 1){ bin = nb1 + (r >> 1);     slot = (r & 1) * 2; }
  else if (cl == 2){ bin = nb1 + nb2 + r;      slot = 0; }
  else             { bin = nb1 + nb2 + nb3 + r; slot = 0; }
  binfo[bin*4 + slot] = g;
}

__device__ __forceinline__ f32x4 mfma4a(f32x4 acc, short8 a0, short8 a1, short8 a2, short8 a3,
                                        const short* __restrict__ wf, int nt, int l){
  acc = __builtin_amdgcn_mfma_f32_16x16x32_bf16(a0, *(const short8*)(wf + ((nt*4+0)*64 + l)*8), acc, 0,0,0);
  acc = __builtin_amdgcn_mfma_f32_16x16x32_bf16(a1, *(const short8*)(wf + ((nt*4+1)*64 + l)*8), acc, 0,0,0);
  acc = __builtin_amdgcn_mfma_f32_16x16x32_bf16(a2, *(const short8*)(wf + ((nt*4+2)*64 + l)*8), acc, 0,0,0);
  acc = __builtin_amdgcn_mfma_f32_16x16x32_bf16(a3, *(const short8*)(wf + ((nt*4+3)*64 + l)*8), acc, 0,0,0);
  return acc;
}
// hi + lo split GEMM tile: X@(Whi+Wlo), fp32 accumulate
__device__ __forceinline__ f32x4 mfma8(short8 a0, short8 a1, short8 a2, short8 a3,
                                       const short* __restrict__ wf, int nt, int l){
  f32x4 acc = {0.f, 0.f, 0.f, 0.f};
  acc = mfma4a(acc, a0, a1, a2, a3, wf, nt, l);
  acc = mfma4a(acc, a0, a1, a2, a3, wf + WF_LO, nt, l);
  return acc;
}

// in-register LN on D-layout regs v[nt][r]: row = 16-lane group; shfl 1,2,4,8 + nt regs
__device__ __forceinline__ void ln_inreg(float (&v)[8][4], const float (&gv)[8], const float (&bv)[8]){
  #pragma unroll
  for (int r = 0; r < 4; ++r){
    float s = 0.f;
    #pragma unroll
    for (int nt = 0; nt < 8; ++nt) s += v[nt][r];
    s += __shfl_xor(s,1); s += __shfl_xor(s,2); s += __shfl_xor(s,4); s += __shfl_xor(s,8);
    float mean = s * (1.f/128.f);
    float q = 0.f;
    #pragma unroll
    for (int nt = 0; nt < 8; ++nt){ float d = v[nt][r] - mean; q += d*d; }
    q += __shfl_xor(q,1); q += __shfl_xor(q,2); q += __shfl_xor(q,4); q += __shfl_xor(q,8);
    float rs = rsqrtf(q*(1.f/128.f) + EPS);
    #pragma unroll
    for (int nt = 0; nt < 8; ++nt) v[nt][r] = (v[nt][r] - mean)*rs*gv[nt] + bv[nt];
  }
}

__global__ __launch_bounds__(256, 3) void gene_bin_kernel(
  const float* __restrict__ RF, const short* __restrict__ wfrag,
  const float* __restrict__ qrow,
  const float* __restrict__ bq, const float* __restrict__ bk,
  const float* __restrict__ bv, const float* __restrict__ bo,
  const float* __restrict__ blin,
  const float* __restrict__ g1, const float* __restrict__ b1,
  const float* __restrict__ g2, const float* __restrict__ b2,
  const int* __restrict__ rxn_idx, const int* __restrict__ starts,
  const int* __restrict__ counts, const int* __restrict__ binfo,
  const int* __restrict__ meta, float* __restrict__ pooled)
{
  // LDS: 2*64*138*2 + 128*72*2 = 53,760 B -> 3 blocks/CU (161,280 <= 163,840)
  __shared__ short xb[64][138];   // activations / Q / P staging
  __shared__ short kb[64][138];   // K / O staging / FF staging / PMA K'
  __shared__ short vt[128][72];   // V^T: vt[d][key]
  __shared__ int mg[4], mL[4], ms0[4], mbase[4];

  if ((int)blockIdx.x >= meta[0]) return;
  const int bin = blockIdx.x;
  const int t = threadIdx.x, w = t >> 6, l = t & 63;
  const int hi = l >> 4, c = l & 15;
  const int r0 = w * 16;

  if (t == 0){
    int s = 0;
    while (s < 4){
      int g = binfo[bin*4 + s];
      if (g >= 0){
        int Lg = counts[g]; if (Lg > LMAX) Lg = LMAX;
        int ntg = (Lg + 15) >> 4;
        for (int u = 0; u < ntg; ++u){ mg[s+u] = g; mL[s+u] = Lg; ms0[s+u] = starts[g]; mbase[s+u] = s; }
        s += ntg;
      } else { mg[s] = -1; mL[s] = 0; ms0[s] = 0; mbase[s] = s; s++; }
    }
  }
  __syncthreads();

  // ---- stage rows (bf16), zero pad rows ----
  for (int idx = t; idx < 64*16; idx += 256){
    int row = idx >> 4, ch = idx & 15;
    int s = row >> 4;
    int g = mg[s];
    int ro = row - mbase[s]*16;
    short8 u = {0,0,0,0,0,0,0,0};
    if (g >= 0 && ro < mL[s]){
      int rr = rxn_idx[ms0[s] + ro];
      const float* src = RF + (size_t)rr*C + ch*8;
      float4 v0 = *(const float4*)(src);
      float4 v1 = *(const float4*)(src + 4);
      u[0]=f2bs(v0.x); u[1]=f2bs(v0.y); u[2]=f2bs(v0.z); u[3]=f2bs(v0.w);
      u[4]=f2bs(v1.x); u[5]=f2bs(v1.y); u[6]=f2bs(v1.z); u[7]=f2bs(v1.w);
    }
    *(short8*)&xb[row][ch*8] = u;
  }
  __syncthreads();

  const int myg  = mg[w];
  const int kbeg = mbase[w]*16;
  const int kend = kbeg + mL[w];

  // residual (D-pattern) from staged input
  float resid[8][4];
  #pragma unroll
  for (int nt = 0; nt < 8; ++nt)
    #pragma unroll
    for (int r = 0; r < 4; ++r)
      resid[nt][r] = b2f(xb[r0 + hi*4 + r][nt*16 + c]);
  WSYNC();

  // ================= encoder SABs (blk 0,1) =================
  #pragma unroll 1
  for (int blk = 0; blk < 2; ++blk){
    const short* wfq = wfrag + (size_t)(0*4 + blk)*16384;
    const short* wfk = wfrag + (size_t)(1*4 + blk)*16384;
    const short* wfv = wfrag + (size_t)(2*4 + blk)*16384;
    const short* wfo = wfrag + (size_t)(3*4 + blk)*16384;
    const short* wfl = wfrag + (size_t)(4*4 + blk)*16384;

    // ---- QKV (wave-local rows); Q staged into own xb rows ----
    {
      short8 ax[4];
      #pragma unroll
      for (int kk = 0; kk < 4; ++kk) ax[kk] = *(const short8*)&xb[r0 + c][kk*32 + hi*8];
      WSYNC();
      #pragma unroll
      for (int nt = 0; nt < 8; ++nt){
        int col = nt*16 + c;
        f32x4 aq = mfma8(ax[0],ax[1],ax[2],ax[3], wfq, nt, l);
        f32x4 ak = mfma8(ax[0],ax[1],ax[2],ax[3], wfk, nt, l);
        f32x4 av = mfma8(ax[0],ax[1],ax[2],ax[3], wfv, nt, l);
        float bqv = bq[blk*C + col], bkv = bk[blk*C + col], bvv = bv[blk*C + col];
        #pragma unroll
        for (int r = 0; r < 4; ++r){
          kb[r0 + hi*4 + r][col] = f2bs(ak[r] + bkv);
          vt[col][r0 + hi*4 + r] = f2bs(av[r] + bvv);
          xb[r0 + hi*4 + r][col] = f2bs(aq[r] + bqv);
        }
      }
    }
    __syncthreads();   // bar A: K,V visible block-wide

    // ---- scores + in-register softmax for all 4 heads ----
    unsigned pp[4][8];
    #pragma unroll
    for (int h = 0; h < 4; ++h){
      short8 qa = *(const short8*)&xb[r0 + c][h*32 + hi*8];
      f32x4 lg[4];
      #pragma unroll
      for (int kt = 0; kt < 4; ++kt){
        f32x4 z = {0.f,0.f,0.f,0.f};
        if (myg >= 0 && mg[kt] == myg)
          z = __builtin_amdgcn_mfma_f32_16x16x32_bf16(qa,
                *(const short8*)&kb[kt*16 + c][h*32 + hi*8], z, 0,0,0);
        lg[kt] = z;
      }
      float P[4][4];
      #pragma unroll
      for (int r = 0; r < 4; ++r){
        float mx = -3.4e38f;
        #pragma unroll
        for (int kt = 0; kt < 4; ++kt){
          int col = kt*16 + c;
          bool ok = (col >= kbeg) && (col < kend);
          float v = ok ? lg[kt][r]*ISQ : -3.4e38f;
          P[kt][r] = v;
          mx = fmaxf(mx, v);
        }
        mx = fmaxf(mx, __shfl_xor(mx,1)); mx = fmaxf(mx, __shfl_xor(mx,2));
        mx = fmaxf(mx, __shfl_xor(mx,4)); mx = fmaxf(mx, __shfl_xor(mx,8));
        float sm = 0.f;
        #pragma unroll
        for (int kt = 0; kt < 4; ++kt){
          int col = kt*16 + c;
          bool ok = (col >= kbeg) && (col < kend);
          float e = ok ? __expf(P[kt][r] - mx) : 0.f;
          P[kt][r] = e; sm += e;
        }
        sm += __shfl_xor(sm,1); sm += __shfl_xor(sm,2);
        sm += __shfl_xor(sm,4); sm += __shfl_xor(sm,8);
        float inv = (sm > 0.f) ? 1.f/sm : 0.f;
        #pragma unroll
        for (int kt = 0; kt < 4; ++kt) P[kt][r] *= inv;
      }
      #pragma unroll
      for (int kt = 0; kt < 4; ++kt){
        pp[h][kt*2+0] = pack2(P[kt][0], P[kt][1]);
        pp[h][kt*2+1] = pack2(P[kt][2], P[kt][3]);
      }
    }
    __syncthreads();   // bar B: all K reads complete

    // ---- PV in head pairs: P staged over dead Q rows (wave-local) ----
    f32x4 O[8];
    {
      f32x4 zz = {0.f,0.f,0.f,0.f};
      #pragma unroll
      for (int nt = 0; nt < 8; ++nt) O[nt] = zz;
    }
    #pragma unroll
    for (int pr = 0; pr < 2; ++pr){
      #pragma unroll
      for (int hh = 0; hh < 2; ++hh){
        int h = pr*2 + hh;
        #pragma unroll
        for (int kt = 0; kt < 4; ++kt)
          #pragma unroll
          for (int r = 0; r < 4; ++r){
            unsigned u = pp[h][kt*2 + (r>>1)];
            xb[r0 + hi*4 + r][hh*64 + kt*16 + c] = (short)((r&1) ? (u >> 16) : (u & 0xFFFF));
          }
      }
      WSYNC();
      #pragma unroll
      for (int hh = 0; hh < 2; ++hh){
        int h = pr*2 + hh;
        #pragma unroll
        for (int dt = 0; dt < 2; ++dt){
          f32x4 acc = O[h*2 + dt];
          #pragma unroll
          for (int ks = 0; ks < 2; ++ks){
            if (kend > ks*32 && kbeg < ks*32 + 32){
              short8 a = *(const short8*)&xb[r0 + c][hh*64 + ks*32 + hi*8];
              short8 b = *(const short8*)&vt[h*32 + dt*16 + c][ks*32 + hi*8];
              acc = __builtin_amdgcn_mfma_f32_16x16x32_bf16(a, b, acc, 0,0,0);
            }
          }
          O[h*2 + dt] = acc;
        }
      }
      WSYNC();
    }

    // ---- Wo + bias + residual, LN1 (in-reg), FF, LN2 (in-reg) ----
    #pragma unroll
    for (int nt = 0; nt < 8; ++nt)
      #pragma unroll
      for (int r = 0; r < 4; ++r)
        kb[r0 + hi*4 + r][nt*16 + c] = f2bs(O[nt][r]);
    WSYNC();
    short8 af[4];
    #pragma unroll
    for (int kk = 0; kk < 4; ++kk) af[kk] = *(const short8*)&kb[r0 + c][kk*32 + hi*8];
    float y[8][4];
    float g1v[8], b1v[8], g2v[8], b2v[8];
    #pragma unroll
    for (int nt = 0; nt < 8; ++nt){
      int col = nt*16 + c;
      g1v[nt] = g1[blk*C + col]; b1v[nt] = b1[blk*C + col];
      g2v[nt] = g2[blk*C + col]; b2v[nt] = b2[blk*C + col];
      f32x4 acc = mfma8(af[0],af[1],af[2],af[3], wfo, nt, l);
      float bb = bo[blk*C + col];
      #pragma unroll
      for (int r = 0; r < 4; ++r) y[nt][r] = acc[r] + bb + resid[nt][r];
    }
    ln_inreg(y, g1v, b1v);
    #pragma unroll
    for (int nt = 0; nt < 8; ++nt)
      #pragma unroll
      for (int r = 0; r < 4; ++r)
        kb[r0 + hi*4 + r][nt*16 + c] = f2bs(y[nt][r]);
    WSYNC();
    short8 af2[4];
    #pragma unroll
    for (int kk = 0; kk < 4; ++kk) af2[kk] = *(const short8*)&kb[r0 + c][kk*32 + hi*8];
    float ff[8][4];
    #pragma unroll
    for (int nt = 0; nt < 8; ++nt){
      int col = nt*16 + c;
      f32x4 acc = mfma8(af2[0],af2[1],af2[2],af2[3], wfl, nt, l);
      float bb = blin[blk*C + col];
      #pragma unroll
      for (int r = 0; r < 4; ++r) ff[nt][r] = y[nt][r] + fmaxf(acc[r] + bb, 0.f);
    }
    ln_inreg(ff, g2v, b2v);
    #pragma unroll
    for (int nt = 0; nt < 8; ++nt)
      #pragma unroll
      for (int r = 0; r < 4; ++r){
        xb[r0 + hi*4 + r][nt*16 + c] = f2bs(ff[nt][r]);
        resid[nt][r] = ff[nt][r];
      }
    __syncthreads();   // bar C: vt/kb reads of this block complete
  }

  // ================= PMA: K',V' projections + per-gene pooling =================
  {
    const short* wfk2 = wfrag + (size_t)(1*4 + 2)*16384;
    const short* wfv2 = wfrag + (size_t)(2*4 + 2)*16384;
    short8 ax[4];
    #pragma unroll
    for (int kk = 0; kk < 4; ++kk) ax[kk] = *(const short8*)&xb[r0 + c][kk*32 + hi*8];
    #pragma unroll
    for (int nt = 0; nt < 8; ++nt){
      int col = nt*16 + c;
      f32x4 ak = mfma8(ax[0],ax[1],ax[2],ax[3], wfk2, nt, l);
      f32x4 av = mfma8(ax[0],ax[1],ax[2],ax[3], wfv2, nt, l);
      float bkv = bk[2*C + col], bvv = bv[2*C + col];
      #pragma unroll
      for (int r = 0; r < 4; ++r){
        kb[r0 + hi*4 + r][col] = f2bs(ak[r] + bkv);
        vt[col][r0 + hi*4 + r] = f2bs(av[r] + bvv);
      }
    }
  }
  __syncthreads();   // bar A': K',V' visible

  if (myg >= 0 && mbase[w] == w){
    int L = mL[w];
    float* ps = (float*)&xb[0][0];   // xb dead; regions disjoint per (w,h)
    #pragma unroll
    for (int h = 0; h < 4; ++h){
      float a = -3.4e38f;
      if (l < L){
        float acc = 0.f;
        #pragma unroll 8
        for (int dd = 0; dd < 32; ++dd)
          acc = fmaf(b2f(kb[r0 + l][h*32 + dd]), qrow[h*32 + dd], acc);
        a = acc * ISQ;
      }
      float mx = wmax(a);
      float e = (l < L) ? __expf(a - mx) : 0.f;
      float s = wsum(e);
      float inv = (s > 0.f) ? 1.f/s : 0.f;
      ps[(w*4 + h)*64 + l] = e * inv;
    }
    WSYNC();
    #pragma unroll
    for (int half = 0; half < 2; ++half){
      int d = l + half*64;
      int h = d >> 5;
      float acc = 0.f;
      for (int kk = 0; kk < L; ++kk)
        acc = fmaf(ps[(w*4 + h)*64 + kk], b2f(vt[d][r0 + kk]), acc);
      pooled[(size_t)myg*C + d] = acc;
    }
  }
}

// ================= fp32 batched tail: PMA post-attn + decoder SAB (16 genes/block) =================
__device__ __forceinline__ void gemmf(const float (*src)[132], const float* __restrict__ W,
                                      float (&o)[8], int col, int rg){
  #pragma unroll
  for (int r = 0; r < 8; ++r) o[r] = 0.f;
  #pragma unroll 4
  for (int k = 0; k < 128; ++k){
    float wv = W[k*C + col];
    #pragma unroll
    for (int r = 0; r < 8; ++r) o[r] = fmaf(src[rg*8 + r][k], wv, o[r]);
  }
}

__device__ __forceinline__ void ln16f(float (*buf)[132], const float* __restrict__ gg,
                                      const float* __restrict__ bb, int t){
  int row = t >> 4, cg = t & 15;
  float v[8]; float s = 0.f;
  #pragma unroll
  for (int k = 0; k < 8; ++k){ v[k] = buf[row][cg*8 + k]; s += v[k]; }
  s += __shfl_xor(s,1); s += __shfl_xor(s,2); s += __shfl_xor(s,4); s += __shfl_xor(s,8);
  float mean = s * (1.f/128.f);
  float q = 0.f;
  #pragma unroll
  for (int k = 0; k < 8; ++k){ float d = v[k] - mean; q += d*d; }
  q += __shfl_xor(q,1); q += __shfl_xor(q,2); q += __shfl_xor(q,4); q += __shfl_xor(q,8);
  float rs = rsqrtf(q*(1.f/128.f) + EPS);
  #pragma unroll
  for (int k = 0; k < 8; ++k)
    buf[row][cg*8 + k] = (v[k] - mean)*rs*gg[cg*8 + k] + bb[cg*8 + k];
}

__global__ __launch_bounds__(256) void tail_kernel(
  const float* __restrict__ pooled,
  const float* __restrict__ Wv, const float* __restrict__ Wo,
  const float* __restrict__ Wlin,
  const float* __restrict__ bv, const float* __restrict__ bo,
  const float* __restrict__ blin,
  const float* __restrict__ g1, const float* __restrict__ b1,
  const float* __restrict__ g2, const float* __restrict__ b2,
  const float* __restrict__ seed, float* __restrict__ out, int G)
{
  __shared__ float ta[16][132];
  __shared__ float tb[16][132];
  const int t = threadIdx.x;
  const int g0 = blockIdx.x * 16;
  const int col = t & 127, rg = t >> 7;   // 8 rows per thread
  float o[8], res[8];

  { // load pooled -> ta
    int row = t >> 4, ch = t & 15;
    float4 v0 = {0,0,0,0}, v1 = {0,0,0,0};
    if (g0 + row < G){
      const float* src = pooled + (size_t)(g0 + row)*C + ch*8;
      v0 = *(const float4*)(src);
      v1 = *(const float4*)(src + 4);
    }
    *(float4*)&ta[row][ch*8] = v0;
    *(float4*)&ta[row][ch*8 + 4] = v1;
  }
  __syncthreads();

  // P1: y = pooled @ Wo2 + bo2 + seed -> tb ; LN1
  gemmf(ta, Wo + 2*C*C, o, col, rg);
  {
    float ss = seed[col], bb = bo[2*C + col];
    #pragma unroll
    for (int r = 0; r < 8; ++r) tb[rg*8 + r][col] = o[r] + bb + ss;
  }
  __syncthreads();
  ln16f(tb, g1 + 2*C, b1 + 2*C, t);
  __syncthreads();
  // P2: ta = tb + relu(tb @ Wlin2 + blin2) ; LN2 -> h3 in ta
  gemmf(tb, Wlin + 2*C*C, o, col, rg);
  {
    float bb = blin[2*C + col];
    #pragma unroll
    for (int r = 0; r < 8; ++r) ta[rg*8 + r][col] = tb[rg*8 + r][col] + fmaxf(o[r] + bb, 0.f);
  }
  __syncthreads();
  ln16f(ta, g2 + 2*C, b2 + 2*C, t);
  __syncthreads();
  // P3: v = h3 @ Wv3 + bv3 -> tb
  gemmf(ta, Wv + 3*C*C, o, col, rg);
  {
    float bb = bv[3*C + col];
    #pragma unroll
    for (int r = 0; r < 8; ++r) tb[rg*8 + r][col] = o[r] + bb;
  }
  __syncthreads();
  // P4: ta = v @ Wo3 + bo3 + h3 ; LN1_3
  gemmf(tb, Wo + 3*C*C, o, col, rg);
  {
    float bb = bo[3*C + col];
    #pragma unroll
    for (int r = 0; r < 8; ++r) res[r] = ta[rg*8 + r][col];
    #pragma unroll
    for (int r = 0; r < 8; ++r) ta[rg*8 + r][col] = o[r] + bb + res[r];
  }
  __syncthreads();
  ln16f(ta, g1 + 3*C, b1 + 3*C, t);
  __syncthreads();
  // P5: tb = ta + relu(ta @ Wlin3 + blin3) ; LN2_3
  gemmf(ta, Wlin + 3*C*C, o, col, rg);
  {
    float bb = blin[3*C + col];
    #pragma unroll
    for (int r = 0; r < 8; ++r) tb[rg*8 + r][col] = ta[rg*8 + r][col] + fmaxf(o[r] + bb, 0.f);
  }
  __syncthreads();
  ln16f(tb, g2 + 3*C, b2 + 3*C, t);
  __syncthreads();
  // P6: nan_to_num + store
  for (int idx = t; idx < 16*128; idx += 256){
    int row = idx >> 7, cc = idx & 127;
    if (g0 + row < G){
      float v = tb[row][cc];
      if (isnan(v)) v = 0.f;
      else if (isinf(v)) v = v > 0 ? 3.402823466e38f : -3.402823466e38f;
      out[(size_t)(g0 + row)*C + cc] = v;
    }
  }
}

extern "C" void kernel_launch(void* const* d_in, const int* in_sizes, int n_in,
                              void* d_out, int out_size, void* d_ws, size_t ws_size,
                              hipStream_t stream){
  const float* RF   = (const float*)d_in[0];
  const float* Wq   = (const float*)d_in[1];
  const float* Wk   = (const float*)d_in[2];
  const float* Wv   = (const float*)d_in[3];
  const float* Wo   = (const float*)d_in[4];
  const float* bq   = (const float*)d_in[5];
  const float* bk   = (const float*)d_in[6];
  const float* bv   = (const float*)d_in[7];
  const float* bo   = (const float*)d_in[8];
  const float* Wlin = (const float*)d_in[9];
  const float* blin = (const float*)d_in[10];
  const float* g1   = (const float*)d_in[11];
  const float* b1   = (const float*)d_in[12];
  const float* g2   = (const float*)d_in[13];
  const float* b2   = (const float*)d_in[14];
  const float* seed = (const float*)d_in[15];
  const int* rxn    = (const int*)d_in[16];
  const int* gidx   = (const int*)d_in[17];

  int E = in_sizes[16];
  int G = out_size / C;

  // ws layout (hi table 655,360 B + lo table 655,360 B)
  char* base = (char*)d_ws;
  short* wfrag = (short*)base;                               // 1,310,720 B
  float* qrow  = (float*)(base + 1310720);                   // 512 B
  int*   meta  = (int*)(base + 1311232);                     // 64 B: [0]=nbins, [1..4]=cnt
  int*   starts= (int*)(base + 1311296);                     // 4G
  int*   counts= (int*)(base + 1311296 + (size_t)4*G);       // 4G
  int*   gcr   = (int*)(base + 1311296 + (size_t)8*G);       // 4G
  int*   binfo = (int*)(base + 1311296 + (size_t)12*G);      // 16G
  float* pooled= (float*)(base + 1311296 + (size_t)28*G);    // 512G

  hipMemsetAsync(meta, 0, 64, stream);
  hipMemsetAsync(binfo, 0xFF, (size_t)16*G, stream);
  prep_wfrag<<<640, 64, 0, stream>>>(Wq, Wk, Wv, Wo, Wlin, wfrag);
  prep_qrow<<<1, 128, 0, stream>>>(seed, Wq, bq, qrow);
  seg_kernel<<<(G + 255)/256, 256, 0, stream>>>(gidx, E, G, starts, counts, meta + 1, gcr);
  fill_kernel<<<(G + 255)/256, 256, 0, stream>>>(G, meta + 1, gcr, binfo, meta);
  gene_bin_kernel<<<G, 256, 0, stream>>>(RF, wfrag, qrow, bq, bk, bv, bo, blin,
      g1, b1, g2, b2, rxn, starts, counts, binfo, meta, pooled);
  tail_kernel<<<(G + 15)/16, 256, 0, stream>>>(pooled, Wv, Wo, Wlin, bv, bo, blin,
      g1, b1, g2, b2, seed, (float*)d_out, G);
}

// Round 10
// 289.629 us; speedup vs baseline: 1.5705x; 1.5705x over previous
//
#include <hip/hip_runtime.h>
#include <hip/hip_bf16.h>
#include <math.h>

#define C 128
#define H 4
#define LMAX 64
#define EPS 1e-5f
#define ISQ 0.17677669529663687f   // 1/sqrt(32)

using short8  = __attribute__((ext_vector_type(8))) short;
using short4v = __attribute__((ext_vector_type(4))) short;
using f32x4   = __attribute__((ext_vector_type(4))) float;

__device__ __forceinline__ float wsum(float v){
  #pragma unroll
  for (int o = 32; o > 0; o >>= 1) v += __shfl_xor(v, o, 64);
  return v;
}
__device__ __forceinline__ float wmax(float v){
  #pragma unroll
  for (int o = 32; o > 0; o >>= 1) v = fmaxf(v, __shfl_xor(v, o, 64));
  return v;
}
__device__ __forceinline__ short f2bs(float f){
  __hip_bfloat16 b = __float2bfloat16(f);   // RNE
  union { __hip_bfloat16 b; short u; } cv; cv.b = b; return cv.u;
}
__device__ __forceinline__ float b2f(short u){
  return __uint_as_float(((unsigned)(unsigned short)u) << 16);
}

// ---- weight fragments: B-operand layout for mfma_f32_16x16x32_bf16 ----
// lane l, j -> W[kt*32 + (l>>4)*8 + j][nt*16 + (l&15)]
__global__ void prep_wfrag(const float* __restrict__ Wq, const float* __restrict__ Wk,
                           const float* __restrict__ Wv, const float* __restrict__ Wo,
                           const float* __restrict__ Wlin, short* __restrict__ wf){
  int bid = blockIdx.x, l = threadIdx.x;
  int tile = bid & 31, mb = bid >> 5;       // mb = mat*4+blk, 0..19
  int mat = mb >> 2, blk = mb & 3;
  const float* W = (mat==0?Wq : mat==1?Wk : mat==2?Wv : mat==3?Wo : Wlin) + blk*C*C;
  int nt = tile >> 2, kt = tile & 3;
  int col = nt*16 + (l & 15);
  int k0  = kt*32 + ((l >> 4) << 3);
  short8 v;
  #pragma unroll
  for (int j = 0; j < 8; j++) v[j] = f2bs(W[(k0 + j)*C + col]);
  *(short8*)(wf + ((size_t)mb*32 + tile)*512 + (size_t)l*8) = v;
}

__global__ void prep_qrow(const float* __restrict__ seed, const float* __restrict__ Wq,
                          const float* __restrict__ bq, float* __restrict__ qrow){
  int t = threadIdx.x;
  const float* wq2 = Wq + 2*C*C;
  float acc = bq[2*C + t];
  #pragma unroll 4
  for (int k = 0; k < C; k++) acc = fmaf(seed[k], wq2[k*C + t], acc);
  qrow[t] = acc;
}

// ---- segment bounds + class ranks ----
__global__ void seg_kernel(const int* __restrict__ gidx, int E, int G,
                           int* __restrict__ starts, int* __restrict__ counts,
                           int* __restrict__ cnt, int* __restrict__ gcr){
  int g = blockIdx.x * blockDim.x + threadIdx.x;
  if (g >= G) return;
  int lo = 0, hi = E;
  while (lo < hi){ int m = (lo + hi) >> 1; if (gidx[m] < g) lo = m + 1; else hi = m; }
  int s = lo; hi = E;
  while (lo < hi){ int m = (lo + hi) >> 1; if (gidx[m] < g + 1) lo = m + 1; else hi = m; }
  starts[g] = s;
  int c_ = lo - s; counts[g] = c_;
  int L = c_ > LMAX ? LMAX : c_; if (L < 1) L = 1;
  int cl = (L - 1) >> 4;
  int r = atomicAdd(&cnt[cl], 1);
  gcr[g] = (cl << 28) | r;
}

// ---- bin assignment from class ranks (deterministic per gene output) ----
__global__ void fill_kernel(int G, const int* __restrict__ cnt, const int* __restrict__ gcr,
                            int* __restrict__ binfo, int* __restrict__ nbins){
  int g = blockIdx.x * blockDim.x + threadIdx.x;
  if (g >= G) return;
  int nb1 = (cnt[0] + 3) >> 2, nb2 = (cnt[1] + 1) >> 1, nb3 = cnt[2];
  if (g == 0) *nbins = nb1 + nb2 + nb3 + cnt[3];
  int v = gcr[g]; int cl = v >> 28; int r = v & 0x0FFFFFFF;
  int bin, slot;
  if      (cl == 0){ bin = r >> 2;             slot = r & 3; }
  else if (cl == 1){ bin = nb1 + (r >> 1);     slot = (r & 1) * 2; }
  else if (cl == 2){ bin = nb1 + nb2 + r;      slot = 0; }
  else             { bin = nb1 + nb2 + nb3 + r; slot = 0; }
  binfo[bin*4 + slot] = g;
}

__device__ __forceinline__ f32x4 mfma4(short8 a0, short8 a1, short8 a2, short8 a3,
                                       const short* __restrict__ wf, int nt, int l){
  f32x4 acc = {0.f, 0.f, 0.f, 0.f};
  acc = __builtin_amdgcn_mfma_f32_16x16x32_bf16(a0, *(const short8*)(wf + ((nt*4+0)*64 + l)*8), acc, 0,0,0);
  acc = __builtin_amdgcn_mfma_f32_16x16x32_bf16(a1, *(const short8*)(wf + ((nt*4+1)*64 + l)*8), acc, 0,0,0);
  acc = __builtin_amdgcn_mfma_f32_16x16x32_bf16(a2, *(const short8*)(wf + ((nt*4+2)*64 + l)*8), acc, 0,0,0);
  acc = __builtin_amdgcn_mfma_f32_16x16x32_bf16(a3, *(const short8*)(wf + ((nt*4+3)*64 + l)*8), acc, 0,0,0);
  return acc;
}

// LN over 64 rows x 128 cols: 4 threads per row, shfl_xor(1,2) group reduce
__device__ __forceinline__ void ln_rows(const short (*src)[136], short (*dst)[136],
                                        const float* __restrict__ gg,
                                        const float* __restrict__ bb, int t){
  int row = t >> 2, q4 = t & 3;
  float v[32];
  float sm = 0.f;
  #pragma unroll
  for (int kk = 0; kk < 32; ++kk){
    float x = b2f(src[row][q4*32 + kk]);
    v[kk] = x; sm += x;
  }
  sm += __shfl_xor(sm, 1);
  sm += __shfl_xor(sm, 2);
  float mean = sm * (1.f/128.f);
  float s2 = 0.f;
  #pragma unroll
  for (int kk = 0; kk < 32; ++kk){ float d = v[kk] - mean; s2 += d*d; }
  s2 += __shfl_xor(s2, 1);
  s2 += __shfl_xor(s2, 2);
  float rs = rsqrtf(s2*(1.f/128.f) + EPS);
  #pragma unroll
  for (int kk = 0; kk < 32; ++kk){
    int col = q4*32 + kk;
    dst[row][col] = f2bs((v[kk] - mean)*rs*gg[col] + bb[col]);
  }
}

__global__ __launch_bounds__(256, 2) void gene_bin_kernel(
  const float* __restrict__ RF, const short* __restrict__ wfrag,
  const float* __restrict__ qrow,
  const float* __restrict__ bq, const float* __restrict__ bk,
  const float* __restrict__ bv, const float* __restrict__ bo,
  const float* __restrict__ blin,
  const float* __restrict__ g1, const float* __restrict__ b1,
  const float* __restrict__ g2, const float* __restrict__ b2,
  const int* __restrict__ rxn_idx, const int* __restrict__ starts,
  const int* __restrict__ counts, const int* __restrict__ binfo,
  const int* __restrict__ meta, float* __restrict__ pooled)
{
  if ((int)blockIdx.x >= meta[0]) return;
  __shared__ short xb[64][136];            // activations (residual source)
  __shared__ short qb[64][136];            // Q, then attn-out (per-head overwrite)
  __shared__ short kb[64][136];            // K, then FF temp, then PMA K
  __shared__ short vt[128][72];            // V^T: vt[d][key]
  __shared__ __align__(16) short sc[64][72]; // logits -> probs (in-place); later aliased fp32 PMA probs
  __shared__ float qrl[C];
  __shared__ int mg[4], mL[4], ms0[4], mbase[4];

  const int bin = blockIdx.x;
  const int t = threadIdx.x, w = t >> 6, l = t & 63;
  const int hi = l >> 4, c = l & 15;

  if (t == 0){
    int s = 0;
    while (s < 4){
      int g = binfo[bin*4 + s];
      if (g >= 0){
        int Lg = counts[g]; if (Lg > LMAX) Lg = LMAX;
        int ntg = (Lg + 15) >> 4;
        for (int u = 0; u < ntg; ++u){ mg[s+u] = g; mL[s+u] = Lg; ms0[s+u] = starts[g]; mbase[s+u] = s; }
        s += ntg;
      } else { mg[s] = -1; mL[s] = 0; ms0[s] = 0; mbase[s] = s; s++; }
    }
  }
  if (t < C) qrl[t] = qrow[t];
  __syncthreads();

  // ---- stage rows (bf16), zero pads; zero sc once (cross-gene cols stay 0 forever) ----
  for (int idx = t; idx < 64*16; idx += 256){
    int row = idx >> 4, ch = idx & 15;
    int s = row >> 4;
    int g = mg[s];
    int ro = row - mbase[s]*16;
    short8 u = {0,0,0,0,0,0,0,0};
    if (g >= 0 && ro < mL[s]){
      int rr = rxn_idx[ms0[s] + ro];
      const float* src = RF + (size_t)rr*C + ch*8;
      float4 v0 = *(const float4*)(src);
      float4 v1 = *(const float4*)(src + 4);
      u[0]=f2bs(v0.x); u[1]=f2bs(v0.y); u[2]=f2bs(v0.z); u[3]=f2bs(v0.w);
      u[4]=f2bs(v1.x); u[5]=f2bs(v1.y); u[6]=f2bs(v1.z); u[7]=f2bs(v1.w);
    }
    *(short8*)&xb[row][ch*8] = u;
  }
  {
    short8 z = {0,0,0,0,0,0,0,0};
    for (int idx = t; idx < 64*9; idx += 256){
      int row = idx / 9, ch = idx - row*9;
      *(short8*)&sc[row][ch*8] = z;
    }
  }
  __syncthreads();

  // ================= encoder SABs (blk 0,1) =================
  for (int blk = 0; blk < 2; ++blk){
    // ---- QKV projections ----
    {
      short8 ax[4][4];
      #pragma unroll
      for (int mt = 0; mt < 4; ++mt)
        #pragma unroll
        for (int kk = 0; kk < 4; ++kk)
          ax[mt][kk] = *(const short8*)&xb[mt*16 + c][kk*32 + hi*8];
      #pragma unroll
      for (int i = 0; i < 6; ++i){
        int pr = w + 4*i;                 // 0..23 = (mat 0..2) x (nt 0..7)
        int mat = pr >> 3, nt = pr & 7;
        const short* wfm = wfrag + (size_t)(mat*4 + blk)*16384;
        const float* bias = (mat == 0 ? bq : mat == 1 ? bk : bv);
        int col = nt*16 + c;
        float bb = bias[blk*C + col];
        #pragma unroll
        for (int mt = 0; mt < 4; ++mt){
          f32x4 acc = mfma4(ax[mt][0], ax[mt][1], ax[mt][2], ax[mt][3], wfm, nt, l);
          if (mat == 2){
            short4v pk;
            #pragma unroll
            for (int r = 0; r < 4; r++) pk[r] = f2bs(acc[r] + bb);
            *(short4v*)&vt[col][mt*16 + hi*4] = pk;     // transposed
          } else if (mat == 0){
            #pragma unroll
            for (int r = 0; r < 4; r++) qb[mt*16 + hi*4 + r][col] = f2bs(acc[r] + bb);
          } else {
            #pragma unroll
            for (int r = 0; r < 4; r++) kb[mt*16 + hi*4 + r][col] = f2bs(acc[r] + bb);
          }
        }
      }
    }
    __syncthreads();

    // ---- attention (heads serialized; block-diagonal over genes) ----
    for (int h = 0; h < H; ++h){
      // scores (bf16 logits into sc, C-layout)
      for (int idx = w; idx < 16; idx += 4){
        int mt = idx >> 2, kt = idx & 3;
        int gm = mg[mt];
        if (gm >= 0 && gm == mg[kt]){
          short8 a = *(const short8*)&qb[mt*16 + c][h*32 + hi*8];
          short8 b = *(const short8*)&kb[kt*16 + c][h*32 + hi*8];
          f32x4 acc = {0.f, 0.f, 0.f, 0.f};
          acc = __builtin_amdgcn_mfma_f32_16x16x32_bf16(a, b, acc, 0,0,0);
          #pragma unroll
          for (int r = 0; r < 4; r++) sc[mt*16 + hi*4 + r][kt*16 + c] = f2bs(acc[r] * ISQ);
        }
      }
      __syncthreads();
      // masked softmax in-place: 4 threads per row, group-reduce
      {
        int row = t >> 2, q4 = t & 3;
        int s = row >> 4;
        if (mg[s] >= 0){
          int kbeg = mbase[s]*16;
          int kend = kbeg + mL[s];
          int send = kbeg + (((mL[s] + 15) >> 4) << 4);
          int b0 = q4*16;
          float e[16];
          float mx = -3.4e38f;
          #pragma unroll
          for (int kk = 0; kk < 16; ++kk){
            int col = b0 + kk;
            bool ok = (col >= kbeg) && (col < kend);
            float lg = ok ? b2f(sc[row][col]) : -3.4e38f;
            e[kk] = lg;
            mx = fmaxf(mx, lg);
          }
          mx = fmaxf(mx, __shfl_xor(mx, 1));
          mx = fmaxf(mx, __shfl_xor(mx, 2));
          float sm = 0.f;
          #pragma unroll
          for (int kk = 0; kk < 16; ++kk){
            int col = b0 + kk;
            bool ok = (col >= kbeg) && (col < kend);
            float ee = ok ? __expf(e[kk] - mx) : 0.f;
            e[kk] = ee; sm += ee;
          }
          sm += __shfl_xor(sm, 1);
          sm += __shfl_xor(sm, 2);
          float inv = 1.f / sm;
          #pragma unroll
          for (int kk = 0; kk < 16; ++kk){
            int col = b0 + kk;
            if (col >= kbeg && col < send)
              sc[row][col] = f2bs((col < kend) ? e[kk]*inv : 0.f);
          }
        }
      }
      __syncthreads();
      // PV -> overwrite Q columns of this head in qb
      for (int idx = w; idx < 8; idx += 4){
        int mt = idx >> 1, dt = idx & 1;
        if (mg[mt] >= 0){
          f32x4 acc = {0.f, 0.f, 0.f, 0.f};
          #pragma unroll
          for (int ks = 0; ks < 2; ++ks){
            short8 a = *(const short8*)&sc[mt*16 + c][ks*32 + hi*8];
            short8 b = *(const short8*)&vt[h*32 + dt*16 + c][ks*32 + hi*8];
            acc = __builtin_amdgcn_mfma_f32_16x16x32_bf16(a, b, acc, 0,0,0);
          }
          int col = h*32 + dt*16 + c;
          #pragma unroll
          for (int r = 0; r < 4; r++) qb[mt*16 + hi*4 + r][col] = f2bs(acc[r]);
        }
      }
      __syncthreads();
    }

    // ---- Wo + bo + residual -> xb ----
    {
      short8 aw[4];
      #pragma unroll
      for (int kk = 0; kk < 4; kk++) aw[kk] = *(const short8*)&qb[w*16 + c][kk*32 + hi*8];
      const short* wfo = wfrag + (size_t)(3*4 + blk)*16384;
      #pragma unroll 2
      for (int nt = 0; nt < 8; ++nt){
        int col = nt*16 + c;
        f32x4 acc = mfma4(aw[0], aw[1], aw[2], aw[3], wfo, nt, l);
        float bb = bo[blk*C + col];
        #pragma unroll
        for (int r = 0; r < 4; r++){
          int row = w*16 + hi*4 + r;
          xb[row][col] = f2bs(acc[r] + bb + b2f(xb[row][col]));
        }
      }
    }
    __syncthreads();
    ln_rows(xb, xb, g1 + blk*C, b1 + blk*C, t);
    __syncthreads();

    // ---- FF -> kb ----
    {
      short8 aw[4];
      #pragma unroll
      for (int kk = 0; kk < 4; kk++) aw[kk] = *(const short8*)&xb[w*16 + c][kk*32 + hi*8];
      const short* wfl = wfrag + (size_t)(4*4 + blk)*16384;
      #pragma unroll 2
      for (int nt = 0; nt < 8; ++nt){
        int col = nt*16 + c;
        f32x4 acc = mfma4(aw[0], aw[1], aw[2], aw[3], wfl, nt, l);
        float bb = blin[blk*C + col];
        #pragma unroll
        for (int r = 0; r < 4; r++){
          int row = w*16 + hi*4 + r;
          kb[row][col] = f2bs(b2f(xb[row][col]) + fmaxf(acc[r] + bb, 0.f));
        }
      }
    }
    __syncthreads();
    ln_rows(kb, xb, g2 + blk*C, b2 + blk*C, t);
    __syncthreads();
  }

  // ================= PMA: K,V projections + per-gene pooling =================
  {
    short8 aw[4];
    #pragma unroll
    for (int kk = 0; kk < 4; kk++) aw[kk] = *(const short8*)&xb[w*16 + c][kk*32 + hi*8];
    const short* wfk2 = wfrag + (size_t)(1*4 + 2)*16384;
    const short* wfv2 = wfrag + (size_t)(2*4 + 2)*16384;
    #pragma unroll 2
    for (int nt = 0; nt < 8; ++nt){
      int col = nt*16 + c;
      f32x4 acc = mfma4(aw[0], aw[1], aw[2], aw[3], wfk2, nt, l);
      float bb = bk[2*C + col];
      #pragma unroll
      for (int r = 0; r < 4; r++) kb[w*16 + hi*4 + r][col] = f2bs(acc[r] + bb);
      acc = mfma4(aw[0], aw[1], aw[2], aw[3], wfv2, nt, l);
      bb = bv[2*C + col];
      short4v pk;
      #pragma unroll
      for (int r = 0; r < 4; r++) pk[r] = f2bs(acc[r] + bb);
      *(short4v*)&vt[col][w*16 + hi*4] = pk;
    }
  }
  __syncthreads();
  // pooling: wave w = slot w (if base slot of a gene)
  {
    int g = mg[w];
    if (g >= 0 && mbase[w] == w){
      int L = mL[w];
      int row = w*16 + l;                // key row in kb / key col in vt
      float* ps = (float*)&sc[0][0];     // sc dead: alias as fp32 probs [slot*4+h][64]
      #pragma unroll
      for (int h = 0; h < 4; ++h){
        float a = -3.4e38f;
        if (l < L){
          float acc = 0.f;
          #pragma unroll 8
          for (int dd = 0; dd < 32; ++dd)
            acc = fmaf(b2f(kb[row][h*32 + dd]), qrl[h*32 + dd], acc);
          a = acc * ISQ;
        }
        float mx = wmax(a);
        float e = (l < L) ? __expf(a - mx) : 0.f;
        float s = wsum(e);
        ps[(w*4 + h)*64 + l] = e / s;
      }
      #pragma unroll
      for (int half = 0; half < 2; ++half){
        int d = l + half*64;
        int h = d >> 5;
        float acc = 0.f;
        for (int kk = 0; kk < L; ++kk)
          acc = fmaf(ps[(w*4 + h)*64 + kk], b2f(vt[d][w*16 + kk]), acc);
        pooled[(size_t)g*C + d] = acc;
      }
    }
  }
}

// ================= fp32 batched tail: PMA post-attn + decoder SAB (16 genes/block) =================
__device__ __forceinline__ void gemmf(const float (*src)[132], const float* __restrict__ W,
                                      float (&o)[8], int col, int rg){
  #pragma unroll
  for (int r = 0; r < 8; ++r) o[r] = 0.f;
  #pragma unroll 4
  for (int k = 0; k < 128; ++k){
    float wv = W[k*C + col];
    #pragma unroll
    for (int r = 0; r < 8; ++r) o[r] = fmaf(src[rg*8 + r][k], wv, o[r]);
  }
}

__device__ __forceinline__ void ln16f(float (*buf)[132], const float* __restrict__ gg,
                                      const float* __restrict__ bb, int t){
  int row = t >> 4, cg = t & 15;
  float v[8]; float s = 0.f;
  #pragma unroll
  for (int k = 0; k < 8; ++k){ v[k] = buf[row][cg*8 + k]; s += v[k]; }
  s += __shfl_xor(s,1); s += __shfl_xor(s,2); s += __shfl_xor(s,4); s += __shfl_xor(s,8);
  float mean = s * (1.f/128.f);
  float q = 0.f;
  #pragma unroll
  for (int k = 0; k < 8; ++k){ float d = v[k] - mean; q += d*d; }
  q += __shfl_xor(q,1); q += __shfl_xor(q,2); q += __shfl_xor(q,4); q += __shfl_xor(q,8);
  float rs = rsqrtf(q*(1.f/128.f) + EPS);
  #pragma unroll
  for (int k = 0; k < 8; ++k)
    buf[row][cg*8 + k] = (v[k] - mean)*rs*gg[cg*8 + k] + bb[cg*8 + k];
}

__global__ __launch_bounds__(256) void tail_kernel(
  const float* __restrict__ pooled,
  const float* __restrict__ Wv, const float* __restrict__ Wo,
  const float* __restrict__ Wlin,
  const float* __restrict__ bv, const float* __restrict__ bo,
  const float* __restrict__ blin,
  const float* __restrict__ g1, const float* __restrict__ b1,
  const float* __restrict__ g2, const float* __restrict__ b2,
  const float* __restrict__ seed, float* __restrict__ out, int G)
{
  __shared__ float ta[16][132];
  __shared__ float tb[16][132];
  const int t = threadIdx.x;
  const int g0 = blockIdx.x * 16;
  const int col = t & 127, rg = t >> 7;   // 8 rows per thread
  float o[8], res[8];

  { // load pooled -> ta
    int row = t >> 4, ch = t & 15;
    float4 v0 = {0,0,0,0}, v1 = {0,0,0,0};
    if (g0 + row < G){
      const float* src = pooled + (size_t)(g0 + row)*C + ch*8;
      v0 = *(const float4*)(src);
      v1 = *(const float4*)(src + 4);
    }
    *(float4*)&ta[row][ch*8] = v0;
    *(float4*)&ta[row][ch*8 + 4] = v1;
  }
  __syncthreads();

  // P1: y = pooled @ Wo2 + bo2 + seed -> tb ; LN1
  gemmf(ta, Wo + 2*C*C, o, col, rg);
  {
    float ss = seed[col], bb = bo[2*C + col];
    #pragma unroll
    for (int r = 0; r < 8; ++r) tb[rg*8 + r][col] = o[r] + bb + ss;
  }
  __syncthreads();
  ln16f(tb, g1 + 2*C, b1 + 2*C, t);
  __syncthreads();
  // P2: ta = tb + relu(tb @ Wlin2 + blin2) ; LN2 -> h3 in ta
  gemmf(tb, Wlin + 2*C*C, o, col, rg);
  {
    float bb = blin[2*C + col];
    #pragma unroll
    for (int r = 0; r < 8; ++r) ta[rg*8 + r][col] = tb[rg*8 + r][col] + fmaxf(o[r] + bb, 0.f);
  }
  __syncthreads();
  ln16f(ta, g2 + 2*C, b2 + 2*C, t);
  __syncthreads();
  // P3: v = h3 @ Wv3 + bv3 -> tb
  gemmf(ta, Wv + 3*C*C, o, col, rg);
  {
    float bb = bv[3*C + col];
    #pragma unroll
    for (int r = 0; r < 8; ++r) tb[rg*8 + r][col] = o[r] + bb;
  }
  __syncthreads();
  // P4: ta = v @ Wo3 + bo3 + h3 ; LN1_3
  gemmf(tb, Wo + 3*C*C, o, col, rg);
  {
    float bb = bo[3*C + col];
    #pragma unroll
    for (int r = 0; r < 8; ++r) res[r] = ta[rg*8 + r][col];
    #pragma unroll
    for (int r = 0; r < 8; ++r) ta[rg*8 + r][col] = o[r] + bb + res[r];
  }
  __syncthreads();
  ln16f(ta, g1 + 3*C, b1 + 3*C, t);
  __syncthreads();
  // P5: tb = ta + relu(ta @ Wlin3 + blin3) ; LN2_3
  gemmf(ta, Wlin + 3*C*C, o, col, rg);
  {
    float bb = blin[3*C + col];
    #pragma unroll
    for (int r = 0; r < 8; ++r) tb[rg*8 + r][col] = ta[rg*8 + r][col] + fmaxf(o[r] + bb, 0.f);
  }
  __syncthreads();
  ln16f(tb, g2 + 3*C, b2 + 3*C, t);
  __syncthreads();
  // P6: nan_to_num + store
  for (int idx = t; idx < 16*128; idx += 256){
    int row = idx >> 7, cc = idx & 127;
    if (g0 + row < G){
      float v = tb[row][cc];
      if (isnan(v)) v = 0.f;
      else if (isinf(v)) v = v > 0 ? 3.402823466e38f : -3.402823466e38f;
      out[(size_t)(g0 + row)*C + cc] = v;
    }
  }
}

extern "C" void kernel_launch(void* const* d_in, const int* in_sizes, int n_in,
                              void* d_out, int out_size, void* d_ws, size_t ws_size,
                              hipStream_t stream){
  const float* RF   = (const float*)d_in[0];
  const float* Wq   = (const float*)d_in[1];
  const float* Wk   = (const float*)d_in[2];
  const float* Wv   = (const float*)d_in[3];
  const float* Wo   = (const float*)d_in[4];
  const float* bq   = (const float*)d_in[5];
  const float* bk   = (const float*)d_in[6];
  const float* bv   = (const float*)d_in[7];
  const float* bo   = (const float*)d_in[8];
  const float* Wlin = (const float*)d_in[9];
  const float* blin = (const float*)d_in[10];
  const float* g1   = (const float*)d_in[11];
  const float* b1   = (const float*)d_in[12];
  const float* g2   = (const float*)d_in[13];
  const float* b2   = (const float*)d_in[14];
  const float* seed = (const float*)d_in[15];
  const int* rxn    = (const int*)d_in[16];
  const int* gidx   = (const int*)d_in[17];

  int E = in_sizes[16];
  int G = out_size / C;

  // ws layout
  char* base = (char*)d_ws;
  short* wfrag = (short*)base;                             // 655360 B
  float* qrow  = (float*)(base + 655360);                  // 512 B
  int*   meta  = (int*)(base + 655872);                    // 64 B: [0]=nbins, [1..4]=cnt
  int*   starts= (int*)(base + 655936);                    // 4G
  int*   counts= (int*)(base + 655936 + (size_t)4*G);      // 4G
  int*   gcr   = (int*)(base + 655936 + (size_t)8*G);      // 4G
  int*   binfo = (int*)(base + 655936 + (size_t)12*G);     // 16G
  float* pooled= (float*)(base + 655936 + (size_t)28*G);   // 512G

  hipMemsetAsync(meta, 0, 64, stream);
  hipMemsetAsync(binfo, 0xFF, (size_t)16*G, stream);
  prep_wfrag<<<640, 64, 0, stream>>>(Wq, Wk, Wv, Wo, Wlin, wfrag);
  prep_qrow<<<1, 128, 0, stream>>>(seed, Wq, bq, qrow);
  seg_kernel<<<(G + 255)/256, 256, 0, stream>>>(gidx, E, G, starts, counts, meta + 1, gcr);
  fill_kernel<<<(G + 255)/256, 256, 0, stream>>>(G, meta + 1, gcr, binfo, meta);
  gene_bin_kernel<<<G, 256, 0, stream>>>(RF, wfrag, qrow, bq, bk, bv, bo, blin,
      g1, b1, g2, b2, rxn, starts, counts, binfo, meta, pooled);
  tail_kernel<<<(G + 15)/16, 256, 0, stream>>>(pooled, Wv, Wo, Wlin, bv, bo, blin,
      g1, b1, g2, b2, seed, (float*)d_out, G);
}

// Round 11
// 272.520 us; speedup vs baseline: 1.6691x; 1.0628x over previous
//
#include <hip/hip_runtime.h>
#include <hip/hip_bf16.h>
#include <math.h>

#define C 128
#define H 4
#define LMAX 64
#define EPS 1e-5f
#define ISQ 0.17677669529663687f   // 1/sqrt(32)

using short8  = __attribute__((ext_vector_type(8))) short;
using short4v = __attribute__((ext_vector_type(4))) short;
using f32x4   = __attribute__((ext_vector_type(4))) float;

__device__ __forceinline__ float wsum(float v){
  #pragma unroll
  for (int o = 32; o > 0; o >>= 1) v += __shfl_xor(v, o, 64);
  return v;
}
__device__ __forceinline__ float wmax(float v){
  #pragma unroll
  for (int o = 32; o > 0; o >>= 1) v = fmaxf(v, __shfl_xor(v, o, 64));
  return v;
}
__device__ __forceinline__ short f2bs(float f){
  __hip_bfloat16 b = __float2bfloat16(f);   // RNE
  union { __hip_bfloat16 b; short u; } cv; cv.b = b; return cv.u;
}
__device__ __forceinline__ float b2f(short u){
  return __uint_as_float(((unsigned)(unsigned short)u) << 16);
}

// ---- weight fragments: B-operand layout for mfma_f32_16x16x32_bf16 ----
// lane l, j -> W[kt*32 + (l>>4)*8 + j][nt*16 + (l&15)]
__global__ void prep_wfrag(const float* __restrict__ Wq, const float* __restrict__ Wk,
                           const float* __restrict__ Wv, const float* __restrict__ Wo,
                           const float* __restrict__ Wlin, short* __restrict__ wf){
  int bid = blockIdx.x, l = threadIdx.x;
  int tile = bid & 31, mb = bid >> 5;       // mb = mat*4+blk, 0..19
  int mat = mb >> 2, blk = mb & 3;
  const float* W = (mat==0?Wq : mat==1?Wk : mat==2?Wv : mat==3?Wo : Wlin) + blk*C*C;
  int nt = tile >> 2, kt = tile & 3;
  int col = nt*16 + (l & 15);
  int k0  = kt*32 + ((l >> 4) << 3);
  short8 v;
  #pragma unroll
  for (int j = 0; j < 8; j++) v[j] = f2bs(W[(k0 + j)*C + col]);
  *(short8*)(wf + ((size_t)mb*32 + tile)*512 + (size_t)l*8) = v;
}

__global__ void prep_qrow(const float* __restrict__ seed, const float* __restrict__ Wq,
                          const float* __restrict__ bq, float* __restrict__ qrow){
  int t = threadIdx.x;
  const float* wq2 = Wq + 2*C*C;
  float acc = bq[2*C + t];
  #pragma unroll 4
  for (int k = 0; k < C; k++) acc = fmaf(seed[k], wq2[k*C + t], acc);
  qrow[t] = acc;
}

// ---- segment bounds + class ranks ----
__global__ void seg_kernel(const int* __restrict__ gidx, int E, int G,
                           int* __restrict__ starts, int* __restrict__ counts,
                           int* __restrict__ cnt, int* __restrict__ gcr){
  int g = blockIdx.x * blockDim.x + threadIdx.x;
  if (g >= G) return;
  int lo = 0, hi = E;
  while (lo < hi){ int m = (lo + hi) >> 1; if (gidx[m] < g) lo = m + 1; else hi = m; }
  int s = lo; hi = E;
  while (lo < hi){ int m = (lo + hi) >> 1; if (gidx[m] < g + 1) lo = m + 1; else hi = m; }
  starts[g] = s;
  int c_ = lo - s; counts[g] = c_;
  int L = c_ > LMAX ? LMAX : c_; if (L < 1) L = 1;
  int cl = (L - 1) >> 4;
  int r = atomicAdd(&cnt[cl], 1);
  gcr[g] = (cl << 28) | r;
}

// ---- bin assignment from class ranks (deterministic per gene output) ----
__global__ void fill_kernel(int G, const int* __restrict__ cnt, const int* __restrict__ gcr,
                            int* __restrict__ binfo, int* __restrict__ nbins){
  int g = blockIdx.x * blockDim.x + threadIdx.x;
  if (g >= G) return;
  int nb1 = (cnt[0] + 3) >> 2, nb2 = (cnt[1] + 1) >> 1, nb3 = cnt[2];
  if (g == 0) *nbins = nb1 + nb2 + nb3 + cnt[3];
  int v = gcr[g]; int cl = v >> 28; int r = v & 0x0FFFFFFF;
  int bin, slot;
  if      (cl == 0){ bin = r >> 2;             slot = r & 3; }
  else if (cl == 1){ bin = nb1 + (r >> 1);     slot = (r & 1) * 2; }
  else if (cl == 2){ bin = nb1 + nb2 + r;      slot = 0; }
  else             { bin = nb1 + nb2 + nb3 + r; slot = 0; }
  binfo[bin*4 + slot] = g;
}

__device__ __forceinline__ f32x4 mfma4(short8 a0, short8 a1, short8 a2, short8 a3,
                                       const short* __restrict__ wf, int nt, int l){
  f32x4 acc = {0.f, 0.f, 0.f, 0.f};
  acc = __builtin_amdgcn_mfma_f32_16x16x32_bf16(a0, *(const short8*)(wf + ((nt*4+0)*64 + l)*8), acc, 0,0,0);
  acc = __builtin_amdgcn_mfma_f32_16x16x32_bf16(a1, *(const short8*)(wf + ((nt*4+1)*64 + l)*8), acc, 0,0,0);
  acc = __builtin_amdgcn_mfma_f32_16x16x32_bf16(a2, *(const short8*)(wf + ((nt*4+2)*64 + l)*8), acc, 0,0,0);
  acc = __builtin_amdgcn_mfma_f32_16x16x32_bf16(a3, *(const short8*)(wf + ((nt*4+3)*64 + l)*8), acc, 0,0,0);
  return acc;
}

// LN over 64 rows x 128 cols: 4 threads per row, shfl_xor(1,2) group reduce.
// row = t>>2 is wave-row-aligned: wave w handles rows [w*16, w*16+16).
__device__ __forceinline__ void ln_rows(const short (*src)[136], short (*dst)[136],
                                        const float* __restrict__ gg,
                                        const float* __restrict__ bb, int t){
  int row = t >> 2, q4 = t & 3;
  float v[32];
  float sm = 0.f;
  #pragma unroll
  for (int kk = 0; kk < 32; ++kk){
    float x = b2f(src[row][q4*32 + kk]);
    v[kk] = x; sm += x;
  }
  sm += __shfl_xor(sm, 1);
  sm += __shfl_xor(sm, 2);
  float mean = sm * (1.f/128.f);
  float s2 = 0.f;
  #pragma unroll
  for (int kk = 0; kk < 32; ++kk){ float d = v[kk] - mean; s2 += d*d; }
  s2 += __shfl_xor(s2, 1);
  s2 += __shfl_xor(s2, 2);
  float rs = rsqrtf(s2*(1.f/128.f) + EPS);
  #pragma unroll
  for (int kk = 0; kk < 32; ++kk){
    int col = q4*32 + kk;
    dst[row][col] = f2bs((v[kk] - mean)*rs*gg[col] + bb[col]);
  }
}

__global__ __launch_bounds__(256, 2) void gene_bin_kernel(
  const float* __restrict__ RF, const short* __restrict__ wfrag,
  const float* __restrict__ qrow,
  const float* __restrict__ bq, const float* __restrict__ bk,
  const float* __restrict__ bv, const float* __restrict__ bo,
  const float* __restrict__ blin,
  const float* __restrict__ g1, const float* __restrict__ b1,
  const float* __restrict__ g2, const float* __restrict__ b2,
  const int* __restrict__ rxn_idx, const int* __restrict__ starts,
  const int* __restrict__ counts, const int* __restrict__ binfo,
  const int* __restrict__ meta, float* __restrict__ pooled)
{
  if ((int)blockIdx.x >= meta[0]) return;
  __shared__ short xb[64][136];            // activations (residual source)
  __shared__ short qb[64][136];            // Q, then attn-out (per-head overwrite; wave-row-private after barA)
  __shared__ short kb[64][136];            // K, then FF temp, then PMA K
  __shared__ short vt[128][72];            // V^T: vt[d][key]
  __shared__ __align__(16) short sc[64][72]; // logits -> probs (in-place; wave-row-private); later fp32 PMA probs
  __shared__ float qrl[C];
  __shared__ int mg[4], mL[4], ms0[4], mbase[4];

  const int bin = blockIdx.x;
  const int t = threadIdx.x, w = t >> 6, l = t & 63;
  const int hi = l >> 4, c = l & 15;

  if (t == 0){
    int s = 0;
    while (s < 4){
      int g = binfo[bin*4 + s];
      if (g >= 0){
        int Lg = counts[g]; if (Lg > LMAX) Lg = LMAX;
        int ntg = (Lg + 15) >> 4;
        for (int u = 0; u < ntg; ++u){ mg[s+u] = g; mL[s+u] = Lg; ms0[s+u] = starts[g]; mbase[s+u] = s; }
        s += ntg;
      } else { mg[s] = -1; mL[s] = 0; ms0[s] = 0; mbase[s] = s; s++; }
    }
  }
  if (t < C) qrl[t] = qrow[t];
  __syncthreads();

  // ---- stage rows (bf16), zero pads; zero sc once (cross-gene cols stay 0 forever) ----
  for (int idx = t; idx < 64*16; idx += 256){
    int row = idx >> 4, ch = idx & 15;
    int s = row >> 4;
    int g = mg[s];
    int ro = row - mbase[s]*16;
    short8 u = {0,0,0,0,0,0,0,0};
    if (g >= 0 && ro < mL[s]){
      int rr = rxn_idx[ms0[s] + ro];
      const float* src = RF + (size_t)rr*C + ch*8;
      float4 v0 = *(const float4*)(src);
      float4 v1 = *(const float4*)(src + 4);
      u[0]=f2bs(v0.x); u[1]=f2bs(v0.y); u[2]=f2bs(v0.z); u[3]=f2bs(v0.w);
      u[4]=f2bs(v1.x); u[5]=f2bs(v1.y); u[6]=f2bs(v1.z); u[7]=f2bs(v1.w);
    }
    *(short8*)&xb[row][ch*8] = u;
  }
  {
    short8 z = {0,0,0,0,0,0,0,0};
    for (int idx = t; idx < 64*9; idx += 256){
      int row = idx / 9, ch = idx - row*9;
      *(short8*)&sc[row][ch*8] = z;
    }
  }
  __syncthreads();

  const int myg = mg[w];

  // ================= encoder SABs (blk 0,1) =================
  for (int blk = 0; blk < 2; ++blk){
    // ---- QKV projections (nt-split across waves) ----
    {
      short8 ax[4][4];
      #pragma unroll
      for (int mt = 0; mt < 4; ++mt)
        #pragma unroll
        for (int kk = 0; kk < 4; ++kk)
          ax[mt][kk] = *(const short8*)&xb[mt*16 + c][kk*32 + hi*8];
      #pragma unroll
      for (int i = 0; i < 6; ++i){
        int pr = w + 4*i;                 // 0..23 = (mat 0..2) x (nt 0..7)
        int mat = pr >> 3, nt = pr & 7;
        const short* wfm = wfrag + (size_t)(mat*4 + blk)*16384;
        const float* bias = (mat == 0 ? bq : mat == 1 ? bk : bv);
        int col = nt*16 + c;
        float bb = bias[blk*C + col];
        #pragma unroll
        for (int mt = 0; mt < 4; ++mt){
          f32x4 acc = mfma4(ax[mt][0], ax[mt][1], ax[mt][2], ax[mt][3], wfm, nt, l);
          if (mat == 2){
            short4v pk;
            #pragma unroll
            for (int r = 0; r < 4; r++) pk[r] = f2bs(acc[r] + bb);
            *(short4v*)&vt[col][mt*16 + hi*4] = pk;     // transposed
          } else if (mat == 0){
            #pragma unroll
            for (int r = 0; r < 4; r++) qb[mt*16 + hi*4 + r][col] = f2bs(acc[r] + bb);
          } else {
            #pragma unroll
            for (int r = 0; r < 4; r++) kb[mt*16 + hi*4 + r][col] = f2bs(acc[r] + bb);
          }
        }
      }
    }
    __syncthreads();   // bar A: Q,K,V visible block-wide

    // ---- attention: wave w owns row-block mt=w -> whole head loop is wave-private ----
    for (int h = 0; h < H; ++h){
      // scores: sc rows [w*16, w*16+16), same addresses/values as before (writer reassigned)
      if (myg >= 0){
        short8 a = *(const short8*)&qb[w*16 + c][h*32 + hi*8];
        #pragma unroll
        for (int kt = 0; kt < 4; ++kt){
          if (mg[kt] == myg){
            short8 b = *(const short8*)&kb[kt*16 + c][h*32 + hi*8];
            f32x4 acc = {0.f, 0.f, 0.f, 0.f};
            acc = __builtin_amdgcn_mfma_f32_16x16x32_bf16(a, b, acc, 0,0,0);
            #pragma unroll
            for (int r = 0; r < 4; r++) sc[w*16 + hi*4 + r][kt*16 + c] = f2bs(acc[r] * ISQ);
          }
        }
      }
      // masked softmax in-place: row = t>>2 (already wave-row-local)
      {
        int row = t >> 2, q4 = t & 3;
        int s = row >> 4;
        if (mg[s] >= 0){
          int kbeg = mbase[s]*16;
          int kend = kbeg + mL[s];
          int send = kbeg + (((mL[s] + 15) >> 4) << 4);
          int b0 = q4*16;
          float e[16];
          float mx = -3.4e38f;
          #pragma unroll
          for (int kk = 0; kk < 16; ++kk){
            int col = b0 + kk;
            bool ok = (col >= kbeg) && (col < kend);
            float lg = ok ? b2f(sc[row][col]) : -3.4e38f;
            e[kk] = lg;
            mx = fmaxf(mx, lg);
          }
          mx = fmaxf(mx, __shfl_xor(mx, 1));
          mx = fmaxf(mx, __shfl_xor(mx, 2));
          float sm = 0.f;
          #pragma unroll
          for (int kk = 0; kk < 16; ++kk){
            int col = b0 + kk;
            bool ok = (col >= kbeg) && (col < kend);
            float ee = ok ? __expf(e[kk] - mx) : 0.f;
            e[kk] = ee; sm += ee;
          }
          sm += __shfl_xor(sm, 1);
          sm += __shfl_xor(sm, 2);
          float inv = 1.f / sm;
          #pragma unroll
          for (int kk = 0; kk < 16; ++kk){
            int col = b0 + kk;
            if (col >= kbeg && col < send)
              sc[row][col] = f2bs((col < kend) ? e[kk]*inv : 0.f);
          }
        }
      }
      // PV: wave w owns mt=w -> reads own sc rows, writes own qb rows (head-h cols)
      if (myg >= 0){
        #pragma unroll
        for (int dt = 0; dt < 2; ++dt){
          f32x4 acc = {0.f, 0.f, 0.f, 0.f};
          #pragma unroll
          for (int ks = 0; ks < 2; ++ks){
            short8 a = *(const short8*)&sc[w*16 + c][ks*32 + hi*8];
            short8 b = *(const short8*)&vt[h*32 + dt*16 + c][ks*32 + hi*8];
            acc = __builtin_amdgcn_mfma_f32_16x16x32_bf16(a, b, acc, 0,0,0);
          }
          int col = h*32 + dt*16 + c;
          #pragma unroll
          for (int r = 0; r < 4; r++) qb[w*16 + hi*4 + r][col] = f2bs(acc[r]);
        }
      }
      // no barriers in the head loop: sc/qb accesses are wave-row-private,
      // kb/vt are read-only here (written before bar A)
    }

    // ---- Wo + bo + residual -> xb (own rows; qb own rows fully written by own wave) ----
    {
      short8 aw[4];
      #pragma unroll
      for (int kk = 0; kk < 4; kk++) aw[kk] = *(const short8*)&qb[w*16 + c][kk*32 + hi*8];
      const short* wfo = wfrag + (size_t)(3*4 + blk)*16384;
      #pragma unroll 2
      for (int nt = 0; nt < 8; ++nt){
        int col = nt*16 + c;
        f32x4 acc = mfma4(aw[0], aw[1], aw[2], aw[3], wfo, nt, l);
        float bb = bo[blk*C + col];
        #pragma unroll
        for (int r = 0; r < 4; r++){
          int row = w*16 + hi*4 + r;
          xb[row][col] = f2bs(acc[r] + bb + b2f(xb[row][col]));
        }
      }
    }
    ln_rows(xb, xb, g1 + blk*C, b1 + blk*C, t);   // own rows; no barrier needed before
    __syncthreads();   // bar B: last cross-wave kb reads (scores) done before FF overwrites kb

    // ---- FF -> kb (own rows) ----
    {
      short8 aw[4];
      #pragma unroll
      for (int kk = 0; kk < 4; kk++) aw[kk] = *(const short8*)&xb[w*16 + c][kk*32 + hi*8];
      const short* wfl = wfrag + (size_t)(4*4 + blk)*16384;
      #pragma unroll 2
      for (int nt = 0; nt < 8; ++nt){
        int col = nt*16 + c;
        f32x4 acc = mfma4(aw[0], aw[1], aw[2], aw[3], wfl, nt, l);
        float bb = blin[blk*C + col];
        #pragma unroll
        for (int r = 0; r < 4; r++){
          int row = w*16 + hi*4 + r;
          kb[row][col] = f2bs(b2f(xb[row][col]) + fmaxf(acc[r] + bb, 0.f));
        }
      }
    }
    ln_rows(kb, xb, g2 + blk*C, b2 + blk*C, t);   // own rows; no barrier needed before
    __syncthreads();   // bar C: next layer's QKV reads ALL xb rows
  }

  // ================= PMA: K,V projections + per-gene pooling =================
  {
    short8 aw[4];
    #pragma unroll
    for (int kk = 0; kk < 4; kk++) aw[kk] = *(const short8*)&xb[w*16 + c][kk*32 + hi*8];
    const short* wfk2 = wfrag + (size_t)(1*4 + 2)*16384;
    const short* wfv2 = wfrag + (size_t)(2*4 + 2)*16384;
    #pragma unroll 2
    for (int nt = 0; nt < 8; ++nt){
      int col = nt*16 + c;
      f32x4 acc = mfma4(aw[0], aw[1], aw[2], aw[3], wfk2, nt, l);
      float bb = bk[2*C + col];
      #pragma unroll
      for (int r = 0; r < 4; r++) kb[w*16 + hi*4 + r][col] = f2bs(acc[r] + bb);
      acc = mfma4(aw[0], aw[1], aw[2], aw[3], wfv2, nt, l);
      bb = bv[2*C + col];
      short4v pk;
      #pragma unroll
      for (int r = 0; r < 4; r++) pk[r] = f2bs(acc[r] + bb);
      *(short4v*)&vt[col][w*16 + hi*4] = pk;
    }
  }
  __syncthreads();   // bar A': K',V' visible (pooling reads cross-wave rows/cols)
  // pooling: wave w = slot w (if base slot of a gene)
  {
    int g = mg[w];
    if (g >= 0 && mbase[w] == w){
      int L = mL[w];
      int row = w*16 + l;                // key row in kb / key col in vt
      float* ps = (float*)&sc[0][0];     // sc dead: alias as fp32 probs [slot*4+h][64]
      #pragma unroll
      for (int h = 0; h < 4; ++h){
        float a = -3.4e38f;
        if (l < L){
          float acc = 0.f;
          #pragma unroll 8
          for (int dd = 0; dd < 32; ++dd)
            acc = fmaf(b2f(kb[row][h*32 + dd]), qrl[h*32 + dd], acc);
          a = acc * ISQ;
        }
        float mx = wmax(a);
        float e = (l < L) ? __expf(a - mx) : 0.f;
        float s = wsum(e);
        ps[(w*4 + h)*64 + l] = e / s;
      }
      #pragma unroll
      for (int half = 0; half < 2; ++half){
        int d = l + half*64;
        int h = d >> 5;
        float acc = 0.f;
        for (int kk = 0; kk < L; ++kk)
          acc = fmaf(ps[(w*4 + h)*64 + kk], b2f(vt[d][w*16 + kk]), acc);
        pooled[(size_t)g*C + d] = acc;
      }
    }
  }
}

// ================= fp32 batched tail: PMA post-attn + decoder SAB (16 genes/block) =================
__device__ __forceinline__ void gemmf(const float (*src)[132], const float* __restrict__ W,
                                      float (&o)[8], int col, int rg){
  #pragma unroll
  for (int r = 0; r < 8; ++r) o[r] = 0.f;
  #pragma unroll 4
  for (int k = 0; k < 128; ++k){
    float wv = W[k*C + col];
    #pragma unroll
    for (int r = 0; r < 8; ++r) o[r] = fmaf(src[rg*8 + r][k], wv, o[r]);
  }
}

__device__ __forceinline__ void ln16f(float (*buf)[132], const float* __restrict__ gg,
                                      const float* __restrict__ bb, int t){
  int row = t >> 4, cg = t & 15;
  float v[8]; float s = 0.f;
  #pragma unroll
  for (int k = 0; k < 8; ++k){ v[k] = buf[row][cg*8 + k]; s += v[k]; }
  s += __shfl_xor(s,1); s += __shfl_xor(s,2); s += __shfl_xor(s,4); s += __shfl_xor(s,8);
  float mean = s * (1.f/128.f);
  float q = 0.f;
  #pragma unroll
  for (int k = 0; k < 8; ++k){ float d = v[k] - mean; q += d*d; }
  q += __shfl_xor(q,1); q += __shfl_xor(q,2); q += __shfl_xor(q,4); q += __shfl_xor(q,8);
  float rs = rsqrtf(q*(1.f/128.f) + EPS);
  #pragma unroll
  for (int k = 0; k < 8; ++k)
    buf[row][cg*8 + k] = (v[k] - mean)*rs*gg[cg*8 + k] + bb[cg*8 + k];
}

__global__ __launch_bounds__(256) void tail_kernel(
  const float* __restrict__ pooled,
  const float* __restrict__ Wv, const float* __restrict__ Wo,
  const float* __restrict__ Wlin,
  const float* __restrict__ bv, const float* __restrict__ bo,
  const float* __restrict__ blin,
  const float* __restrict__ g1, const float* __restrict__ b1,
  const float* __restrict__ g2, const float* __restrict__ b2,
  const float* __restrict__ seed, float* __restrict__ out, int G)
{
  __shared__ float ta[16][132];
  __shared__ float tb[16][132];
  const int t = threadIdx.x;
  const int g0 = blockIdx.x * 16;
  const int col = t & 127, rg = t >> 7;   // 8 rows per thread
  float o[8], res[8];

  { // load pooled -> ta
    int row = t >> 4, ch = t & 15;
    float4 v0 = {0,0,0,0}, v1 = {0,0,0,0};
    if (g0 + row < G){
      const float* src = pooled + (size_t)(g0 + row)*C + ch*8;
      v0 = *(const float4*)(src);
      v1 = *(const float4*)(src + 4);
    }
    *(float4*)&ta[row][ch*8] = v0;
    *(float4*)&ta[row][ch*8 + 4] = v1;
  }
  __syncthreads();

  // P1: y = pooled @ Wo2 + bo2 + seed -> tb ; LN1
  gemmf(ta, Wo + 2*C*C, o, col, rg);
  {
    float ss = seed[col], bb = bo[2*C + col];
    #pragma unroll
    for (int r = 0; r < 8; ++r) tb[rg*8 + r][col] = o[r] + bb + ss;
  }
  __syncthreads();
  ln16f(tb, g1 + 2*C, b1 + 2*C, t);
  __syncthreads();
  // P2: ta = tb + relu(tb @ Wlin2 + blin2) ; LN2 -> h3 in ta
  gemmf(tb, Wlin + 2*C*C, o, col, rg);
  {
    float bb = blin[2*C + col];
    #pragma unroll
    for (int r = 0; r < 8; ++r) ta[rg*8 + r][col] = tb[rg*8 + r][col] + fmaxf(o[r] + bb, 0.f);
  }
  __syncthreads();
  ln16f(ta, g2 + 2*C, b2 + 2*C, t);
  __syncthreads();
  // P3: v = h3 @ Wv3 + bv3 -> tb
  gemmf(ta, Wv + 3*C*C, o, col, rg);
  {
    float bb = bv[3*C + col];
    #pragma unroll
    for (int r = 0; r < 8; ++r) tb[rg*8 + r][col] = o[r] + bb;
  }
  __syncthreads();
  // P4: ta = v @ Wo3 + bo3 + h3 ; LN1_3
  gemmf(tb, Wo + 3*C*C, o, col, rg);
  {
    float bb = bo[3*C + col];
    #pragma unroll
    for (int r = 0; r < 8; ++r) res[r] = ta[rg*8 + r][col];
    #pragma unroll
    for (int r = 0; r < 8; ++r) ta[rg*8 + r][col] = o[r] + bb + res[r];
  }
  __syncthreads();
  ln16f(ta, g1 + 3*C, b1 + 3*C, t);
  __syncthreads();
  // P5: tb = ta + relu(ta @ Wlin3 + blin3) ; LN2_3
  gemmf(ta, Wlin + 3*C*C, o, col, rg);
  {
    float bb = blin[3*C + col];
    #pragma unroll
    for (int r = 0; r < 8; ++r) tb[rg*8 + r][col] = ta[rg*8 + r][col] + fmaxf(o[r] + bb, 0.f);
  }
  __syncthreads();
  ln16f(tb, g2 + 3*C, b2 + 3*C, t);
  __syncthreads();
  // P6: nan_to_num + store
  for (int idx = t; idx < 16*128; idx += 256){
    int row = idx >> 7, cc = idx & 127;
    if (g0 + row < G){
      float v = tb[row][cc];
      if (isnan(v)) v = 0.f;
      else if (isinf(v)) v = v > 0 ? 3.402823466e38f : -3.402823466e38f;
      out[(size_t)(g0 + row)*C + cc] = v;
    }
  }
}

extern "C" void kernel_launch(void* const* d_in, const int* in_sizes, int n_in,
                              void* d_out, int out_size, void* d_ws, size_t ws_size,
                              hipStream_t stream){
  const float* RF   = (const float*)d_in[0];
  const float* Wq   = (const float*)d_in[1];
  const float* Wk   = (const float*)d_in[2];
  const float* Wv   = (const float*)d_in[3];
  const float* Wo   = (const float*)d_in[4];
  const float* bq   = (const float*)d_in[5];
  const float* bk   = (const float*)d_in[6];
  const float* bv   = (const float*)d_in[7];
  const float* bo   = (const float*)d_in[8];
  const float* Wlin = (const float*)d_in[9];
  const float* blin = (const float*)d_in[10];
  const float* g1   = (const float*)d_in[11];
  const float* b1   = (const float*)d_in[12];
  const float* g2   = (const float*)d_in[13];
  const float* b2   = (const float*)d_in[14];
  const float* seed = (const float*)d_in[15];
  const int* rxn    = (const int*)d_in[16];
  const int* gidx   = (const int*)d_in[17];

  int E = in_sizes[16];
  int G = out_size / C;

  // ws layout
  char* base = (char*)d_ws;
  short* wfrag = (short*)base;                             // 655360 B
  float* qrow  = (float*)(base + 655360);                  // 512 B
  int*   meta  = (int*)(base + 655872);                    // 64 B: [0]=nbins, [1..4]=cnt
  int*   starts= (int*)(base + 655936);                    // 4G
  int*   counts= (int*)(base + 655936 + (size_t)4*G);      // 4G
  int*   gcr   = (int*)(base + 655936 + (size_t)8*G);      // 4G
  int*   binfo = (int*)(base + 655936 + (size_t)12*G);     // 16G
  float* pooled= (float*)(base + 655936 + (size_t)28*G);   // 512G

  hipMemsetAsync(meta, 0, 64, stream);
  hipMemsetAsync(binfo, 0xFF, (size_t)16*G, stream);
  prep_wfrag<<<640, 64, 0, stream>>>(Wq, Wk, Wv, Wo, Wlin, wfrag);
  prep_qrow<<<1, 128, 0, stream>>>(seed, Wq, bq, qrow);
  seg_kernel<<<(G + 255)/256, 256, 0, stream>>>(gidx, E, G, starts, counts, meta + 1, gcr);
  fill_kernel<<<(G + 255)/256, 256, 0, stream>>>(G, meta + 1, gcr, binfo, meta);
  gene_bin_kernel<<<G, 256, 0, stream>>>(RF, wfrag, qrow, bq, bk, bv, bo, blin,
      g1, b1, g2, b2, rxn, starts, counts, binfo, meta, pooled);
  tail_kernel<<<(G + 15)/16, 256, 0, stream>>>(pooled, Wv, Wo, Wlin, bv, bo, blin,
      g1, b1, g2, b2, seed, (float*)d_out, G);
}